// Round 1
// baseline (426.076 us; speedup 1.0000x reference)
//
#include <hip/hip_runtime.h>
#include <hip/hip_bf16.h>
#include <cstdint>
#include <cstddef>

typedef __attribute__((ext_vector_type(8))) short short8;
typedef __attribute__((ext_vector_type(4))) short short4v;
typedef __attribute__((ext_vector_type(4))) float floatx4;

#define LOG2E 1.44269504088896340736f

__device__ __forceinline__ unsigned short f2bf(float f) {
    unsigned u = __float_as_uint(f);
    u += 0x7FFFu + ((u >> 16) & 1u);   // RNE
    return (unsigned short)(u >> 16);
}
__device__ __forceinline__ float bf2f(unsigned short s) {
    return __uint_as_float(((unsigned)s) << 16);
}

// ---------------------------------------------------------------------------
// Kernel 1: hT[b][o][j] = sum_k x[b][j][k] * W[o][k], output bf16, o-major
// (transposed so the attention kernel's A-operand frags are contiguous 16B).
// Grid: (M/64=256, F_out/64=4), 256 threads (4 waves). Each wave: 16 j-rows
// x 64 o-cols = 4 C-tiles of 16x16, K-loop 8 steps of 32.
// ---------------------------------------------------------------------------
__global__ __launch_bounds__(256) void gemm_h(const float* __restrict__ x,
                                              const float* __restrict__ W,
                                              unsigned short* __restrict__ hT) {
    const int w = threadIdx.x >> 6, lane = threadIdx.x & 63;
    const int q = lane >> 4, t16 = lane & 15;
    const int jrow = blockIdx.x * 64 + w * 16 + t16;   // A m-index
    const int ob   = blockIdx.y * 64;

    floatx4 acc[4] = {};
#pragma unroll 2
    for (int kb = 0; kb < 8; ++kb) {
        const int k0 = kb * 32 + q * 8;
        const float4* ax = (const float4*)(x + (size_t)jrow * 256 + k0);
        float4 a0 = ax[0], a1 = ax[1];
        short8 af;
        af[0] = (short)f2bf(a0.x); af[1] = (short)f2bf(a0.y);
        af[2] = (short)f2bf(a0.z); af[3] = (short)f2bf(a0.w);
        af[4] = (short)f2bf(a1.x); af[5] = (short)f2bf(a1.y);
        af[6] = (short)f2bf(a1.z); af[7] = (short)f2bf(a1.w);
#pragma unroll
        for (int ct = 0; ct < 4; ++ct) {
            const int orow = ob + ct * 16 + t16;       // B n-index (W is Bᵀ)
            const float4* bx = (const float4*)(W + (size_t)orow * 256 + k0);
            float4 b0 = bx[0], b1 = bx[1];
            short8 bf;
            bf[0] = (short)f2bf(b0.x); bf[1] = (short)f2bf(b0.y);
            bf[2] = (short)f2bf(b0.z); bf[3] = (short)f2bf(b0.w);
            bf[4] = (short)f2bf(b1.x); bf[5] = (short)f2bf(b1.y);
            bf[6] = (short)f2bf(b1.z); bf[7] = (short)f2bf(b1.w);
            acc[ct] = __builtin_amdgcn_mfma_f32_16x16x32_bf16(af, bf, acc[ct], 0, 0, 0);
        }
    }
    // C/D: col = lane&15 -> o_local, row = q*4+reg -> j_local
    const int jbase = blockIdx.x * 64 + w * 16 + q * 4;
    const int b = jbase >> 11, jj = jbase & 2047;
#pragma unroll
    for (int ct = 0; ct < 4; ++ct) {
        const int o = ob + ct * 16 + t16;
        short4v sv;
        sv[0] = (short)f2bf(acc[ct][0]);
        sv[1] = (short)f2bf(acc[ct][1]);
        sv[2] = (short)f2bf(acc[ct][2]);
        sv[3] = (short)f2bf(acc[ct][3]);
        *(short4v*)(hT + ((size_t)b * 256 + o) * 2048 + jj) = sv;
    }
}

// ---------------------------------------------------------------------------
// Kernel 2: s_src[j] = sum_o hT[b][o][j]*a_src[o]; same for s_dst.
// Grid: 256 blocks x 256 threads; block handles 64 consecutive flat rows j,
// 4 o-quarters reduced through LDS. Loads coalesced (lanes = consecutive j).
// ---------------------------------------------------------------------------
__global__ __launch_bounds__(256) void s_kernel(const unsigned short* __restrict__ hT,
                                                const float* __restrict__ a_src,
                                                const float* __restrict__ a_dst,
                                                float* __restrict__ s_src,
                                                float* __restrict__ s_dst) {
    const int jl = threadIdx.x & 63;
    const int oq = threadIdx.x >> 6;
    const int jg = blockIdx.x * 64 + jl;
    const int b = jg >> 11, jj = jg & 2047;
    const unsigned short* base = hT + (size_t)b * 256 * 2048 + jj;
    float ps = 0.f, pd = 0.f;
#pragma unroll 8
    for (int t = 0; t < 64; ++t) {
        const int o = oq * 64 + t;
        float h = bf2f(base[(size_t)o * 2048]);
        ps = __fmaf_rn(h, a_src[o], ps);
        pd = __fmaf_rn(h, a_dst[o], pd);
    }
    __shared__ float rs[256], rd[256];
    rs[threadIdx.x] = ps; rd[threadIdx.x] = pd;
    __syncthreads();
    if (threadIdx.x < 64) {
        s_src[jg] = rs[jl] + rs[jl + 64] + rs[jl + 128] + rs[jl + 192];
        s_dst[jg] = rd[jl] + rd[jl + 64] + rd[jl + 128] + rd[jl + 192];
    }
}

// ---------------------------------------------------------------------------
// Kernel 3: fused masked softmax-attention.
// Oᵀ = hᵀ · αᵀ  with α generated in registers in MFMA B-frag layout.
// Unnormalized weights p = exp2(LOG2E*lrelu(ss_i+sd_j)) * (adj!=0); row sums l
// accumulated via an all-ones A-operand MFMA; epilogue scales by 1/l.
// Grid: 512 blocks (b x 64 i-blocks of 32 rows), 256 threads (4 waves):
// wave -> (i-tile = w&1, o-half = w>>1): 8 o-tiles + ones tile.
// ---------------------------------------------------------------------------
__global__ __launch_bounds__(256) void attn(const unsigned short* __restrict__ hT,
                                            const int* __restrict__ adj,
                                            const float* __restrict__ s_src,
                                            const float* __restrict__ s_dst,
                                            float* __restrict__ out) {
    const int w = threadIdx.x >> 6, lane = threadIdx.x & 63;
    const int q = lane >> 4, t16 = lane & 15;
    const int b  = blockIdx.x >> 6;
    const int i0 = (blockIdx.x & 63) * 32;
    const int itile = i0 + (w & 1) * 16;
    const int i = itile + t16;                 // this lane's attention row
    const int oh = (w >> 1) * 128;             // o-half handled by this wave

    const float si = s_src[b * 2048 + i] * LOG2E;
    const unsigned short* hTb = hT + (size_t)b * 256 * 2048;
    const int* adjrow = adj + (size_t)(b * 2048 + i) * 2048;
    const float* sdb = s_dst + b * 2048;

    floatx4 accO[8] = {};
    floatx4 accL = {};
    short8 ones;
#pragma unroll
    for (int e = 0; e < 8; ++e) ones[e] = (short)0x3F80;  // bf16 1.0

    const unsigned short* pa = hTb + (size_t)(oh + t16) * 2048 + q * 8;

#pragma unroll 2
    for (int kb = 0; kb < 64; ++kb) {
        const int jq = kb * 32 + q * 8;
        const int4* ap = (const int4*)(adjrow + jq);
        int4 m0 = ap[0], m1 = ap[1];
        const float4* dp = (const float4*)(sdb + jq);
        float4 d0 = dp[0], d1 = dp[1];

        float sdv[8] = {d0.x, d0.y, d0.z, d0.w, d1.x, d1.y, d1.z, d1.w};
        int   mv[8]  = {m0.x, m0.y, m0.z, m0.w, m1.x, m1.y, m1.z, m1.w};

        short8 bfrag;   // alpha[i = lane&15][j = jq + e]  (B-frag layout)
#pragma unroll
        for (int e = 0; e < 8; ++e) {
            float t  = __fmaf_rn(sdv[e], LOG2E, si);   // LOG2E*(ss+sd)
            float lr = fmaxf(t, 0.2f * t);             // leaky-relu (c>0 commutes)
            float pe = __builtin_amdgcn_exp2f(lr);
            pe = (mv[e] != 0) ? pe : 0.0f;
            bfrag[e] = (short)f2bf(pe);
        }

        const unsigned short* pk = pa + kb * 32;
#pragma unroll
        for (int ct = 0; ct < 8; ++ct) {
            short8 af = *(const short8*)(pk + (size_t)ct * 16 * 2048);
            accO[ct] = __builtin_amdgcn_mfma_f32_16x16x32_bf16(af, bfrag, accO[ct], 0, 0, 0);
        }
        accL = __builtin_amdgcn_mfma_f32_16x16x32_bf16(ones, bfrag, accL, 0, 0, 0);
    }

    // ones-MFMA rows are all identical: accL[r] = l_i for this lane's col i
    const float l = accL[0];
    const float rl = l > 0.f ? 1.f / l : 0.f;

    // C/D: col = lane&15 -> i, row = q*4+reg -> o_local
    float* orow = out + ((size_t)(b * 2048 + i)) * 256 + oh + q * 4;
#pragma unroll
    for (int ct = 0; ct < 8; ++ct) {
        floatx4 v = accO[ct] * rl;
        *(floatx4*)(orow + ct * 16) = v;
    }
}

extern "C" void kernel_launch(void* const* d_in, const int* in_sizes, int n_in,
                              void* d_out, int out_size, void* d_ws, size_t ws_size,
                              hipStream_t stream) {
    const float* x     = (const float*)d_in[0];
    const int*   adj   = (const int*)d_in[1];
    const float* W     = (const float*)d_in[2];
    const float* a_src = (const float*)d_in[3];
    const float* a_dst = (const float*)d_in[4];
    float* out = (float*)d_out;

    unsigned short* hT = (unsigned short*)d_ws;                       // 8 MB
    float* s_src = (float*)((char*)d_ws + (size_t)8 * 1024 * 1024);   // 64 KB
    float* s_dst = s_src + 16384;                                     // 64 KB

    gemm_h<<<dim3(256, 4), 256, 0, stream>>>(x, W, hT);
    s_kernel<<<256, 256, 0, stream>>>(hT, a_src, a_dst, s_src, s_dst);
    attn<<<512, 256, 0, stream>>>(hT, adj, s_src, s_dst, out);
}

// Round 2
// 291.220 us; speedup vs baseline: 1.4631x; 1.4631x over previous
//
#include <hip/hip_runtime.h>
#include <hip/hip_bf16.h>
#include <cstdint>
#include <cstddef>

typedef __attribute__((ext_vector_type(8))) short short8;
typedef __attribute__((ext_vector_type(4))) short short4v;
typedef __attribute__((ext_vector_type(4))) float floatx4;

#define LOG2E 1.44269504088896340736f

__device__ __forceinline__ unsigned short f2bf(float f) {
    unsigned u = __float_as_uint(f);
    u += 0x7FFFu + ((u >> 16) & 1u);   // RNE
    return (unsigned short)(u >> 16);
}
__device__ __forceinline__ float bf2f(unsigned short s) {
    return __uint_as_float(((unsigned)s) << 16);
}

// ---------------------------------------------------------------------------
// Kernel 0: pack W (fp32 256x256) -> bf16, so gemm_h waves don't re-convert.
// ---------------------------------------------------------------------------
__global__ __launch_bounds__(256) void wprep(const float* __restrict__ W,
                                             unsigned short* __restrict__ Wb) {
    int t = blockIdx.x * 256 + threadIdx.x;   // 16384 float4's
    float4 v = ((const float4*)W)[t];
    short4v s;
    s[0] = (short)f2bf(v.x); s[1] = (short)f2bf(v.y);
    s[2] = (short)f2bf(v.z); s[3] = (short)f2bf(v.w);
    ((short4v*)Wb)[t] = s;
}

// ---------------------------------------------------------------------------
// Kernel 1: hT[b][o][j] = sum_k x[b][j][k] * W[o][k]  (bf16 out, o-major).
// B operand comes pre-packed from Wb (L1/L2-resident short8 loads).
// ---------------------------------------------------------------------------
__global__ __launch_bounds__(256) void gemm_h(const float* __restrict__ x,
                                              const unsigned short* __restrict__ Wb,
                                              unsigned short* __restrict__ hT) {
    const int w = threadIdx.x >> 6, lane = threadIdx.x & 63;
    const int q = lane >> 4, t16 = lane & 15;
    const int jrow = blockIdx.x * 64 + w * 16 + t16;
    const int ob   = blockIdx.y * 64;

    floatx4 acc[4] = {};
#pragma unroll
    for (int kb = 0; kb < 8; ++kb) {
        const int k0 = kb * 32 + q * 8;
        const float4* ax = (const float4*)(x + (size_t)jrow * 256 + k0);
        float4 a0 = ax[0], a1 = ax[1];
        short8 af;
        af[0] = (short)f2bf(a0.x); af[1] = (short)f2bf(a0.y);
        af[2] = (short)f2bf(a0.z); af[3] = (short)f2bf(a0.w);
        af[4] = (short)f2bf(a1.x); af[5] = (short)f2bf(a1.y);
        af[6] = (short)f2bf(a1.z); af[7] = (short)f2bf(a1.w);
#pragma unroll
        for (int ct = 0; ct < 4; ++ct) {
            short8 bf = *(const short8*)(Wb + (size_t)(ob + ct * 16 + t16) * 256 + k0);
            acc[ct] = __builtin_amdgcn_mfma_f32_16x16x32_bf16(af, bf, acc[ct], 0, 0, 0);
        }
    }
    const int jbase = blockIdx.x * 64 + w * 16 + q * 4;
    const int b = jbase >> 11, jj = jbase & 2047;
#pragma unroll
    for (int ct = 0; ct < 4; ++ct) {
        const int o = ob + ct * 16 + t16;
        short4v sv;
        sv[0] = (short)f2bf(acc[ct][0]);
        sv[1] = (short)f2bf(acc[ct][1]);
        sv[2] = (short)f2bf(acc[ct][2]);
        sv[3] = (short)f2bf(acc[ct][3]);
        *(short4v*)(hT + ((size_t)b * 256 + o) * 2048 + jj) = sv;
    }
}

// ---------------------------------------------------------------------------
// Kernel 2: s_src/s_dst = hT . a_src/a_dst.  512 threads, 8 o-groups of 32.
// ---------------------------------------------------------------------------
__global__ __launch_bounds__(512) void s_kernel(const unsigned short* __restrict__ hT,
                                                const float* __restrict__ a_src,
                                                const float* __restrict__ a_dst,
                                                float* __restrict__ s_src,
                                                float* __restrict__ s_dst) {
    const int jl = threadIdx.x & 63;
    const int og = threadIdx.x >> 6;          // 0..7
    const int jg = blockIdx.x * 64 + jl;
    const int b = jg >> 11, jj = jg & 2047;
    const unsigned short* base = hT + (size_t)b * 256 * 2048 + jj;
    float ps = 0.f, pd = 0.f;
#pragma unroll 8
    for (int u = 0; u < 32; ++u) {
        const int o = og * 32 + u;
        float h = bf2f(base[(size_t)o * 2048]);
        ps = __fmaf_rn(h, a_src[o], ps);
        pd = __fmaf_rn(h, a_dst[o], pd);
    }
    __shared__ float rs[512], rd[512];
    rs[threadIdx.x] = ps; rd[threadIdx.x] = pd;
    __syncthreads();
    if (threadIdx.x < 64) {
        float a = 0.f, d = 0.f;
#pragma unroll
        for (int g = 0; g < 8; ++g) { a += rs[g * 64 + jl]; d += rd[g * 64 + jl]; }
        s_src[jg] = a; s_dst[jg] = d;
    }
}

// ---------------------------------------------------------------------------
// Kernel 3: fused masked-softmax attention, producer/consumer pipeline.
// Block: 32 i-rows x 256 o. Chunk = 128 j. adj loaded coalesced (512B runs)
// one chunk ahead into regs; p = exp2(lrelu) computed once, ds_written to a
// double-buffered LDS tile in B-frag layout; 4 waves (o-quarters) consume.
// Row sums via VALU + LDS reduction (no ones-MFMA).
// ---------------------------------------------------------------------------
__global__ __launch_bounds__(256, 2) void attn(const unsigned short* __restrict__ hT,
                                               const int* __restrict__ adj,
                                               const float* __restrict__ s_src,
                                               const float* __restrict__ s_dst,
                                               float* __restrict__ out) {
    const int tid = threadIdx.x;
    const int w = tid >> 6, lane = tid & 63;
    const int q = lane >> 4, t16 = lane & 15;
    const int b = blockIdx.y;
    const int i0 = blockIdx.x * 32;

    __shared__ float sd_lds[2048];
    __shared__ float si_lds[32];
    __shared__ unsigned short p_lds[2][32][136];   // +8 pad, 16B-aligned rows
    __shared__ float lred[32][33];
    __shared__ float rl_lds[32];

    // Stage s_dst (pre-scaled by log2e) and s_src for this block's rows.
    const float* sdb = s_dst + (size_t)b * 2048;
#pragma unroll
    for (int k = 0; k < 2; ++k) {
        int idx = (k * 256 + tid) * 4;
        float4 v = *(const float4*)(sdb + idx);
        v.x *= LOG2E; v.y *= LOG2E; v.z *= LOG2E; v.w *= LOG2E;
        *(float4*)(&sd_lds[idx]) = v;
    }
    if (tid < 32) si_lds[tid] = s_src[(size_t)b * 2048 + i0 + tid] * LOG2E;
    __syncthreads();

    // Producer duty: rows rg+8k (k=0..3), 4 cols jc..jc+3 per chunk.
    const int rg = tid >> 5;          // 0..7
    const int jc = (tid & 31) * 4;    // 0..124
    const int* adjb = adj + ((size_t)b * 2048 + i0) * 2048;
    float si[4];
#pragma unroll
    for (int k = 0; k < 4; ++k) si[k] = si_lds[rg + 8 * k];

    float lsum[4] = {0.f, 0.f, 0.f, 0.f};
    int4 adjv[4];

    const unsigned short* hTw = hT + ((size_t)b * 256 + w * 64 + t16) * 2048 + q * 8;
    floatx4 accO[2][4] = {};

    // prologue: stage + produce chunk 0
#pragma unroll
    for (int k = 0; k < 4; ++k)
        adjv[k] = *(const int4*)(adjb + (size_t)(rg + 8 * k) * 2048 + jc);
    {
        float4 sdv = *(const float4*)(&sd_lds[jc]);
        float sdl[4] = {sdv.x, sdv.y, sdv.z, sdv.w};
        unsigned short* pb = &p_lds[0][0][0];
#pragma unroll
        for (int k = 0; k < 4; ++k) {
            int mv[4] = {adjv[k].x, adjv[k].y, adjv[k].z, adjv[k].w};
            short4v sv;
#pragma unroll
            for (int e = 0; e < 4; ++e) {
                float t = si[k] + sdl[e];
                float lr = fmaxf(t, 0.2f * t);
                float pe = __builtin_amdgcn_exp2f(lr);
                pe = (mv[e] != 0) ? pe : 0.0f;
                unsigned short pu = f2bf(pe);
                sv[e] = (short)pu;
                lsum[k] += bf2f(pu);
            }
            *(short4v*)(pb + (rg + 8 * k) * 136 + jc) = sv;
        }
    }
    __syncthreads();

    for (int c = 0; c < 16; ++c) {
        // stage adj for chunk c+1 (issued before the MFMA block hides it)
        if (c < 15) {
#pragma unroll
            for (int k = 0; k < 4; ++k)
                adjv[k] = *(const int4*)(adjb + (size_t)(rg + 8 * k) * 2048 + (c + 1) * 128 + jc);
        }
        // consume buf[c&1]
        const unsigned short* pb = &p_lds[c & 1][0][0];
#pragma unroll
        for (int ks = 0; ks < 4; ++ks) {
            short8 bf0 = *(const short8*)(pb + t16 * 136 + ks * 32 + q * 8);
            short8 bf1 = *(const short8*)(pb + (16 + t16) * 136 + ks * 32 + q * 8);
#pragma unroll
            for (int ct = 0; ct < 4; ++ct) {
                short8 af = *(const short8*)(hTw + (size_t)ct * 16 * 2048 + c * 128 + ks * 32);
                accO[0][ct] = __builtin_amdgcn_mfma_f32_16x16x32_bf16(af, bf0, accO[0][ct], 0, 0, 0);
                accO[1][ct] = __builtin_amdgcn_mfma_f32_16x16x32_bf16(af, bf1, accO[1][ct], 0, 0, 0);
            }
        }
        // produce p for chunk c+1 into buf[(c+1)&1]
        if (c < 15) {
            float4 sdv = *(const float4*)(&sd_lds[(c + 1) * 128 + jc]);
            float sdl[4] = {sdv.x, sdv.y, sdv.z, sdv.w};
            unsigned short* pw = &p_lds[(c + 1) & 1][0][0];
#pragma unroll
            for (int k = 0; k < 4; ++k) {
                int mv[4] = {adjv[k].x, adjv[k].y, adjv[k].z, adjv[k].w};
                short4v sv;
#pragma unroll
                for (int e = 0; e < 4; ++e) {
                    float t = si[k] + sdl[e];
                    float lr = fmaxf(t, 0.2f * t);
                    float pe = __builtin_amdgcn_exp2f(lr);
                    pe = (mv[e] != 0) ? pe : 0.0f;
                    unsigned short pu = f2bf(pe);
                    sv[e] = (short)pu;
                    lsum[k] += bf2f(pu);
                }
                *(short4v*)(pw + (rg + 8 * k) * 136 + jc) = sv;
            }
        }
        __syncthreads();
    }

    // reduce row sums: lred[row][colgroup]
#pragma unroll
    for (int k = 0; k < 4; ++k) lred[rg + 8 * k][tid & 31] = lsum[k];
    __syncthreads();
    if (tid < 32) {
        float s = 0.f;
#pragma unroll
        for (int u = 0; u < 32; ++u) s += lred[tid][u];
        rl_lds[tid] = (s > 0.f) ? 1.0f / s : 0.0f;
    }
    __syncthreads();

    // epilogue: C[m=o_local][n=i_local]; col=lane&15 -> i, row=q*4+r -> o
#pragma unroll
    for (int it = 0; it < 2; ++it) {
        const float rl = rl_lds[it * 16 + t16];
        float* orow = out + ((size_t)b * 2048 + i0 + it * 16 + t16) * 256 + w * 64 + q * 4;
#pragma unroll
        for (int ct = 0; ct < 4; ++ct) {
            floatx4 v = accO[it][ct] * rl;
            *(floatx4*)(orow + ct * 16) = v;
        }
    }
}

extern "C" void kernel_launch(void* const* d_in, const int* in_sizes, int n_in,
                              void* d_out, int out_size, void* d_ws, size_t ws_size,
                              hipStream_t stream) {
    const float* x     = (const float*)d_in[0];
    const int*   adj   = (const int*)d_in[1];
    const float* W     = (const float*)d_in[2];
    const float* a_src = (const float*)d_in[3];
    const float* a_dst = (const float*)d_in[4];
    float* out = (float*)d_out;

    unsigned short* hT = (unsigned short*)d_ws;                        // 8 MB
    float* s_src = (float*)((char*)d_ws + (size_t)8 * 1024 * 1024);    // 64 KB
    float* s_dst = s_src + 16384;                                      // 64 KB
    unsigned short* Wb = (unsigned short*)(s_dst + 16384);             // 128 KB

    wprep<<<64, 256, 0, stream>>>(W, Wb);
    gemm_h<<<dim3(256, 4), 256, 0, stream>>>(x, Wb, hT);
    s_kernel<<<256, 512, 0, stream>>>(hT, a_src, a_dst, s_src, s_dst);
    attn<<<dim3(64, 8), 256, 0, stream>>>(hT, adj, s_src, s_dst, out);
}

// Round 4
// 274.363 us; speedup vs baseline: 1.5530x; 1.0614x over previous
//
#include <hip/hip_runtime.h>
#include <hip/hip_bf16.h>
#include <cstdint>
#include <cstddef>

typedef __attribute__((ext_vector_type(8))) short short8;
typedef __attribute__((ext_vector_type(4))) short short4v;
typedef __attribute__((ext_vector_type(4))) float floatx4;
typedef unsigned short ushort_t;

#define LOG2E 1.44269504088896340736f

__device__ __forceinline__ unsigned short f2bf(float f) {
    unsigned u = __float_as_uint(f);
    u += 0x7FFFu + ((u >> 16) & 1u);   // RNE
    return (unsigned short)(u >> 16);
}
__device__ __forceinline__ float bf2f(unsigned short s) {
    return __uint_as_float(((unsigned)s) << 16);
}

// ---------------------------------------------------------------------------
// wprep: W fp32 (256x256) -> bf16 once.
// ---------------------------------------------------------------------------
__global__ __launch_bounds__(256) void wprep(const float* __restrict__ W,
                                             ushort_t* __restrict__ Wb) {
    int t = blockIdx.x * 256 + threadIdx.x;   // 16384 float4s
    float4 v = ((const float4*)W)[t];
    short4v s;
    s[0] = (short)f2bf(v.x); s[1] = (short)f2bf(v.y);
    s[2] = (short)f2bf(v.z); s[3] = (short)f2bf(v.w);
    ((short4v*)Wb)[t] = s;
}

// ---------------------------------------------------------------------------
// gemm_h: hT[b][o][j] = sum_k x[b][j][k]*W[o][k]  (bf16 out, o-major).
// Block = 64 j-rows x ALL 256 o  ->  x fp32 read exactly once from HBM.
// W staged in LDS in four 32KB K-quarters (LDS <= 36 KB).
// Epilogue: hT store + full s_src/s_dst (no atomics, written once).
// ---------------------------------------------------------------------------
__global__ __launch_bounds__(256) void gemm_h(const float* __restrict__ x,
                                              const ushort_t* __restrict__ Wb,
                                              ushort_t* __restrict__ hT,
                                              const float* __restrict__ a_src,
                                              const float* __restrict__ a_dst,
                                              float* __restrict__ s_src,
                                              float* __restrict__ s_dst) {
    const int tid = threadIdx.x;
    const int w = tid >> 6, lane = tid & 63;
    const int q = lane >> 4, t16 = lane & 15;

    __shared__ ushort_t wt[256][72];   // 256 o-rows x 64 k (quarter), +8 pad

    // load this wave's 16 x-rows (fp32 -> bf16 A-frags, all K upfront)
    const int jrow = blockIdx.x * 64 + w * 16 + t16;
    const float* xr = x + (size_t)jrow * 256 + q * 8;
    short8 af[8];
#pragma unroll
    for (int kb = 0; kb < 8; ++kb) {
        float4 v0 = *(const float4*)(xr + kb * 32);
        float4 v1 = *(const float4*)(xr + kb * 32 + 4);
        short8 a;
        a[0] = (short)f2bf(v0.x); a[1] = (short)f2bf(v0.y);
        a[2] = (short)f2bf(v0.z); a[3] = (short)f2bf(v0.w);
        a[4] = (short)f2bf(v1.x); a[5] = (short)f2bf(v1.y);
        a[6] = (short)f2bf(v1.z); a[7] = (short)f2bf(v1.w);
        af[kb] = a;
    }

    floatx4 acc[16] = {};
#pragma unroll
    for (int kp = 0; kp < 4; ++kp) {
        if (kp) __syncthreads();       // protect wt overwrite
        // stage W K-quarter: 2048 int4s, 8 per thread
#pragma unroll
        for (int r = 0; r < 8; ++r) {
            int G = tid + 256 * r;
            int row = G >> 3, g = G & 7;
            int4 wv = *(const int4*)(Wb + (size_t)row * 256 + kp * 64 + g * 8);
            *(int4*)(&wt[row][g * 8]) = wv;
        }
        __syncthreads();
#pragma unroll
        for (int ks = 0; ks < 2; ++ks) {
#pragma unroll
            for (int ct = 0; ct < 16; ++ct) {
                short8 bf = *(const short8*)(&wt[ct * 16 + t16][ks * 32 + q * 8]);
                acc[ct] = __builtin_amdgcn_mfma_f32_16x16x32_bf16(af[kp * 2 + ks], bf, acc[ct], 0, 0, 0);
            }
        }
    }

    // hT store: D col=t16 -> o_local, row=q*4+r -> j_local
    const int jbase = blockIdx.x * 64 + w * 16 + q * 4;   // flat b*2048+j
    const int b = jbase >> 11, jj = jbase & 2047;
#pragma unroll
    for (int ct = 0; ct < 16; ++ct) {
        const int o = ct * 16 + t16;
        short4v sv;
        sv[0] = (short)f2bf(acc[ct][0]);
        sv[1] = (short)f2bf(acc[ct][1]);
        sv[2] = (short)f2bf(acc[ct][2]);
        sv[3] = (short)f2bf(acc[ct][3]);
        *(short4v*)(hT + ((size_t)b * 256 + o) * 2048 + jj) = sv;
    }

    // s_src/s_dst: full dot over o (16 cts in-lane, then 16-lane shuffle)
    float psv[4] = {}, pdv[4] = {};
#pragma unroll
    for (int ct = 0; ct < 16; ++ct) {
        const int o = ct * 16 + t16;
        float as = a_src[o], ad = a_dst[o];
#pragma unroll
        for (int r = 0; r < 4; ++r) {
            psv[r] = __fmaf_rn(acc[ct][r], as, psv[r]);
            pdv[r] = __fmaf_rn(acc[ct][r], ad, pdv[r]);
        }
    }
#pragma unroll
    for (int m = 1; m < 16; m <<= 1) {
#pragma unroll
        for (int r = 0; r < 4; ++r) {
            psv[r] += __shfl_xor(psv[r], m);
            pdv[r] += __shfl_xor(pdv[r], m);
        }
    }
    if (t16 == 0) {
#pragma unroll
        for (int r = 0; r < 4; ++r) {
            s_src[jbase + r] = psv[r];
            s_dst[jbase + r] = pdv[r];
        }
    }
}

// ---------------------------------------------------------------------------
// attn: O[i][o] = (1/l_i) sum_j p[i][j] * hT[o][j],
// p = exp2(lrelu(si+sd)*log2e) masked by adj (read directly, streamed).
// Block = 64 i x 256 o, grid (b=8, iblk=32) -> same-b blocks share XCD L2
// for the 1MB hT slice. 64 chunks of 32 j; adj+hT prefetched into regs one
// chunk ahead; hT tile + p tile double-buffered in LDS; 1 barrier/chunk.
// Waves: w -> (o-half = (w&1)*128, i-half = (w>>1)*32).
// ---------------------------------------------------------------------------
__global__ __launch_bounds__(256) void attn(const ushort_t* __restrict__ hT,
                                            const int* __restrict__ adj,
                                            const float* __restrict__ s_src,
                                            const float* __restrict__ s_dst,
                                            float* __restrict__ out) {
    const int tid = threadIdx.x;
    const int w = tid >> 6, lane = tid & 63;
    const int q = lane >> 4, t16 = lane & 15;
    const int b = blockIdx.x;
    const int i0 = blockIdx.y * 64;

    __shared__ ushort_t hts[2][256][40];  // 256 o x 32 j (+8 pad) : 40 KB
    __shared__ ushort_t ps[2][64][40];    // 64 i x 32 j (+8 pad)  : 10 KB
    __shared__ float sdl[2048];           // s_dst * log2e          : 8 KB
    __shared__ float lred[64][5];
    __shared__ float rll[64];

    // stage s_dst*log2e
    const float* sdb = s_dst + (size_t)b * 2048;
#pragma unroll
    for (int k = 0; k < 2; ++k) {
        int idx = (k * 256 + tid) * 4;
        float4 v = *(const float4*)(sdb + idx);
        v.x *= LOG2E; v.y *= LOG2E; v.z *= LOG2E; v.w *= LOG2E;
        *(float4*)(&sdl[idx]) = v;
    }

    // producer mapping: row = tid&63, j-subrange = (tid>>6)*8 within chunk
    const int prow = tid & 63, jh = tid >> 6;
    const float si = s_src[(size_t)b * 2048 + i0 + prow] * LOG2E;
    const int* adjr = adj + ((size_t)b * 2048 + i0 + prow) * 2048 + jh * 8;
    const ushort_t* hTg = hT + ((size_t)b * 256 + tid) * 2048;

    const int osub = (w & 1) * 128, ih = (w >> 1) * 32;

    floatx4 acc[8][2] = {};
    float lsum = 0.f;
    int4 hreg[4];
    int4 a0, a1;

    // prologue: prefetch chunk 0
#pragma unroll
    for (int g = 0; g < 4; ++g)
        hreg[g] = *(const int4*)(hTg + g * 8);
    a0 = *(const int4*)(adjr);
    a1 = *(const int4*)(adjr + 4);
    __syncthreads();   // sdl ready

    for (int c = 0; c < 64; ++c) {
        const int buf = c & 1;
        // stage hT chunk from regs
#pragma unroll
        for (int g = 0; g < 4; ++g)
            *(int4*)(&hts[buf][tid][g * 8]) = hreg[g];
        // produce p tile (8 elems/thread)
        {
            float4 s0 = *(const float4*)(&sdl[c * 32 + jh * 8]);
            float4 s1 = *(const float4*)(&sdl[c * 32 + jh * 8 + 4]);
            float sdv[8] = {s0.x, s0.y, s0.z, s0.w, s1.x, s1.y, s1.z, s1.w};
            int mv[8] = {a0.x, a0.y, a0.z, a0.w, a1.x, a1.y, a1.z, a1.w};
            short8 pv;
#pragma unroll
            for (int e = 0; e < 8; ++e) {
                float t = si + sdv[e];
                float lr = fmaxf(t, 0.2f * t);
                float pe = __builtin_amdgcn_exp2f(lr);
                pe = (mv[e] != 0) ? pe : 0.0f;
                unsigned short u = f2bf(pe);
                lsum += bf2f(u);
                pv[e] = (short)u;
            }
            *(short8*)(&ps[buf][prow][jh * 8]) = pv;
        }
        // prefetch chunk c+1 (regs; latency hidden across barrier)
        if (c < 63) {
#pragma unroll
            for (int g = 0; g < 4; ++g)
                hreg[g] = *(const int4*)(hTg + (c + 1) * 32 + g * 8);
            a0 = *(const int4*)(adjr + (c + 1) * 32);
            a1 = *(const int4*)(adjr + (c + 1) * 32 + 4);
        }
        __syncthreads();
        // consume: K=32 (one kstep), wave tile 32i x 128o
        short8 bf0 = *(const short8*)(&ps[buf][ih + t16][q * 8]);
        short8 bf1 = *(const short8*)(&ps[buf][ih + 16 + t16][q * 8]);
#pragma unroll
        for (int ct = 0; ct < 8; ++ct) {
            short8 af = *(const short8*)(&hts[buf][osub + ct * 16 + t16][q * 8]);
            acc[ct][0] = __builtin_amdgcn_mfma_f32_16x16x32_bf16(af, bf0, acc[ct][0], 0, 0, 0);
            acc[ct][1] = __builtin_amdgcn_mfma_f32_16x16x32_bf16(af, bf1, acc[ct][1], 0, 0, 0);
        }
    }

    // row sums -> 1/l
    lred[prow][jh] = lsum;
    __syncthreads();
    if (tid < 64) {
        float s = lred[tid][0] + lred[tid][1] + lred[tid][2] + lred[tid][3];
        rll[tid] = (s > 0.f) ? 1.0f / s : 0.0f;
    }
    __syncthreads();

    // epilogue: D col=t16 -> i_local, row=q*4+r -> o_local
#pragma unroll
    for (int it = 0; it < 2; ++it) {
        const int i = ih + it * 16 + t16;
        const float rl = rll[i];
        float* orow = out + ((size_t)b * 2048 + i0 + i) * 256 + osub + q * 4;
#pragma unroll
        for (int ct = 0; ct < 8; ++ct) {
            floatx4 v = acc[ct][it] * rl;
            *(floatx4*)(orow + ct * 16) = v;
        }
    }
}

extern "C" void kernel_launch(void* const* d_in, const int* in_sizes, int n_in,
                              void* d_out, int out_size, void* d_ws, size_t ws_size,
                              hipStream_t stream) {
    const float* x     = (const float*)d_in[0];
    const int*   adj   = (const int*)d_in[1];
    const float* W     = (const float*)d_in[2];
    const float* a_src = (const float*)d_in[3];
    const float* a_dst = (const float*)d_in[4];
    float* out = (float*)d_out;

    // 8.25 MB total scratch (round-2-proven footprint)
    char* ws = (char*)d_ws;
    ushort_t* hT = (ushort_t*)ws;                                   // [0, 8M)
    float* s_src = (float*)(ws + (size_t)8 * 1024 * 1024);          // 64 KB
    float* s_dst = s_src + 16384;                                   // 64 KB
    ushort_t* Wb = (ushort_t*)(s_dst + 16384);                      // 128 KB

    wprep<<<64, 256, 0, stream>>>(W, Wb);
    gemm_h<<<256, 256, 0, stream>>>(x, Wb, hT, a_src, a_dst, s_src, s_dst);
    attn<<<dim3(8, 32), 256, 0, stream>>>(hT, adj, s_src, s_dst, out);
}